// Round 1
// baseline (206.074 us; speedup 1.0000x reference)
//
#include <hip/hip_runtime.h>

// NGP hash-grid encode + fused MLP (16->64->32->2, leaky_relu 0.01)
// N=524288 points, L=8 levels, T=65536 table entries, F=2 features.
// Outputs (concat flat): sigma_clipped[N], alpha_scaled[N], zeros[N].

#define NPTS 524288
#define TTAB 65536
#define PI2 2654435761u
#define PI3 805459861u

__global__ __launch_bounds__(256) void ngp_kernel(
    const float* __restrict__ x,
    const float* __restrict__ gridp,
    const float* __restrict__ w0,
    const float* __restrict__ b0,
    const float* __restrict__ w1,
    const float* __restrict__ b1,
    const float* __restrict__ w2,
    const float* __restrict__ b2,
    float* __restrict__ out)
{
    // Weights staged in LDS; w0 transposed to [j][k] so the 16 inputs for
    // output-neuron j are contiguous (4x ds_read_b128). w1 rows are already
    // contiguous. All in-loop reads are wave-uniform -> LDS broadcast.
    __shared__ __align__(16) float sw0t[64 * 16];
    __shared__ __align__(16) float sw1[64 * 32];
    __shared__ __align__(16) float sw2t[64];
    __shared__ __align__(16) float sb0[64];
    __shared__ __align__(16) float sb1[32];
    __shared__ float sb2[2];

    const int tid = threadIdx.x;

    for (int i = tid; i < 64 * 16; i += 256) {
        int k = i >> 6, j = i & 63;          // w0 is (16,64) row-major: w0[k][j]
        sw0t[j * 16 + k] = w0[i];
    }
    for (int i = tid; i < 64 * 32; i += 256) sw1[i] = w1[i];
    if (tid < 64) {
        sw2t[(tid & 1) * 32 + (tid >> 1)] = w2[tid];  // w2 (32,2) -> w2t[m][k]
        sb0[tid] = b0[tid];
    }
    if (tid < 32) sb1[tid] = b1[tid];
    if (tid < 2)  sb2[tid] = b2[tid];
    __syncthreads();

    const int n = blockIdx.x * 256 + tid;
    const float px = x[n * 3 + 0];
    const float py = x[n * 3 + 1];
    const float pz = x[n * 3 + 2];

    const float levels[8] = {2.0f, 2.6946f, 3.6301f, 4.8907f,
                             6.5893f, 8.8766f, 11.959f, 16.111f};

    const float2* __restrict__ gtab = (const float2*)gridp;

    float enc[16];
    #pragma unroll
    for (int l = 0; l < 8; ++l) {
        const float lev = levels[l];
        float xs0 = px * lev, xs1 = py * lev, xs2 = pz * lev;
        float fl0 = floorf(xs0), fl1 = floorf(xs1), fl2 = floorf(xs2);
        float fx = xs0 - fl0, fy = xs1 - fl1, fz = xs2 - fl2;
        unsigned cx = (unsigned)(int)fl0;
        unsigned cy = (unsigned)(int)fl1;
        unsigned cz = (unsigned)(int)fl2;
        unsigned hbase = cx + cy * PI2 + cz * PI3;   // mod 2^32 wrap == jnp.uint32

        float e0 = 0.f, e1 = 0.f;
        #pragma unroll
        for (int c = 0; c < 8; ++c) {
            const int oi = (c >> 2) & 1;   // OFFSETS order: i outer, j mid, k inner
            const int oj = (c >> 1) & 1;
            const int ok = c & 1;
            // hash delta is a compile-time constant per corner
            unsigned idx = (hbase + (unsigned)oi + (unsigned)oj * PI2
                                  + (unsigned)ok * PI3) & (TTAB - 1u);
            float wgt = (oi ? fx : 1.f - fx)
                      * (oj ? fy : 1.f - fy)
                      * (ok ? fz : 1.f - fz);
            float2 ft = gtab[l * TTAB + (int)idx];
            e0 = fmaf(wgt, ft.x, e0);
            e1 = fmaf(wgt, ft.y, e1);
        }
        enc[l * 2 + 0] = e0;
        enc[l * 2 + 1] = e1;
    }

    // Fused MLP: layer0 (16->64) + leaky, streamed into layer1 accumulators
    // (64->32) so h0 never materializes.
    float h1[32];
    #pragma unroll
    for (int k = 0; k < 32; ++k) h1[k] = 0.f;

    #pragma unroll 4
    for (int j = 0; j < 64; ++j) {
        const float4* __restrict__ wr = (const float4*)&sw0t[j * 16];
        float4 wa = wr[0], wb = wr[1], wc = wr[2], wd = wr[3];
        float a = sb0[j];
        a = fmaf(enc[0],  wa.x, a);
        a = fmaf(enc[1],  wa.y, a);
        a = fmaf(enc[2],  wa.z, a);
        a = fmaf(enc[3],  wa.w, a);
        a = fmaf(enc[4],  wb.x, a);
        a = fmaf(enc[5],  wb.y, a);
        a = fmaf(enc[6],  wb.z, a);
        a = fmaf(enc[7],  wb.w, a);
        a = fmaf(enc[8],  wc.x, a);
        a = fmaf(enc[9],  wc.y, a);
        a = fmaf(enc[10], wc.z, a);
        a = fmaf(enc[11], wc.w, a);
        a = fmaf(enc[12], wd.x, a);
        a = fmaf(enc[13], wd.y, a);
        a = fmaf(enc[14], wd.z, a);
        a = fmaf(enc[15], wd.w, a);
        a = (a > 0.f) ? a : 0.01f * a;   // leaky_relu

        const float4* __restrict__ w1r = (const float4*)&sw1[j * 32];
        #pragma unroll
        for (int k4 = 0; k4 < 8; ++k4) {
            float4 ww = w1r[k4];
            h1[k4 * 4 + 0] = fmaf(a, ww.x, h1[k4 * 4 + 0]);
            h1[k4 * 4 + 1] = fmaf(a, ww.y, h1[k4 * 4 + 1]);
            h1[k4 * 4 + 2] = fmaf(a, ww.z, h1[k4 * 4 + 2]);
            h1[k4 * 4 + 3] = fmaf(a, ww.w, h1[k4 * 4 + 3]);
        }
    }

    // Layer 2: 32 -> 2
    float s0 = sb2[0], s1 = sb2[1];
    #pragma unroll
    for (int k = 0; k < 32; ++k) {
        float hk = h1[k] + sb1[k];
        hk = (hk > 0.f) ? hk : 0.01f * hk;
        s0 = fmaf(hk, sw2t[k], s0);
        s1 = fmaf(hk, sw2t[32 + k], s1);
    }

    // Epilogue: sigma clip, alpha scale, zeros.
    out[n]            = (s0 > -1.0f) ? s0 : 0.0f;
    out[NPTS + n]     = fminf(0.0f, s1) * 0.1f;
    out[2 * NPTS + n] = 0.0f;
}

extern "C" void kernel_launch(void* const* d_in, const int* in_sizes, int n_in,
                              void* d_out, int out_size, void* d_ws, size_t ws_size,
                              hipStream_t stream) {
    const float* x    = (const float*)d_in[0];
    const float* grid = (const float*)d_in[1];
    const float* w0   = (const float*)d_in[2];
    const float* b0   = (const float*)d_in[3];
    const float* w1   = (const float*)d_in[4];
    const float* b1   = (const float*)d_in[5];
    const float* w2   = (const float*)d_in[6];
    const float* b2   = (const float*)d_in[7];
    float* out = (float*)d_out;

    ngp_kernel<<<NPTS / 256, 256, 0, stream>>>(x, grid, w0, b0, w1, b1, w2, b2, out);
}